// Round 1
// baseline (1501.572 us; speedup 1.0000x reference)
//
#include <hip/hip_runtime.h>
#include <math.h>

#define Nn 100000
#define Cc 256
#define Dd 32
#define Hh 8
#define SEMk 128
#define PAD 32
#define NEG 0.2f

// K1: h = x @ W^T   (x: N x 256, W: 32 x 256 row-major, h: N x 32)
// block 256 = 32 nodes x 8 dim-quads; x,W read from global (W is L1-hot, x HBM stream)
__global__ __launch_bounds__(256) void k_hproj(const float* __restrict__ x,
                                               const float* __restrict__ W,
                                               float* __restrict__ h) {
    int t = threadIdx.x;
    int n = blockIdx.x * 32 + (t >> 3);
    int dq = t & 7;
    const float4* x4 = (const float4*)x + (size_t)n * 64;
    const float4* W4 = (const float4*)W;
    float4 acc = make_float4(0.f, 0.f, 0.f, 0.f);
#pragma unroll 4
    for (int j4 = 0; j4 < 64; ++j4) {
        float4 xv = x4[j4];
        float4 w0 = W4[(dq * 4 + 0) * 64 + j4];
        float4 w1 = W4[(dq * 4 + 1) * 64 + j4];
        float4 w2 = W4[(dq * 4 + 2) * 64 + j4];
        float4 w3 = W4[(dq * 4 + 3) * 64 + j4];
        acc.x += xv.x * w0.x + xv.y * w0.y + xv.z * w0.z + xv.w * w0.w;
        acc.y += xv.x * w1.x + xv.y * w1.y + xv.z * w1.z + xv.w * w1.w;
        acc.z += xv.x * w2.x + xv.y * w2.y + xv.z * w2.z + xv.w * w2.w;
        acc.w += xv.x * w3.x + xv.y * w3.y + xv.z * w3.z + xv.w * w3.w;
    }
    ((float4*)h)[(size_t)n * 8 + dq] = acc;
}

// K2: per-node attention projections for both layers.
// s_dst[n,hh] = h[n] . att[hh, 0:32]; s_src[n,hh] = h[n] . att[hh, 32:64]
__global__ __launch_bounds__(256) void k_satt(const float* __restrict__ h,
                                              const float* __restrict__ att1,
                                              const float* __restrict__ att2,
                                              float* __restrict__ sd1, float* __restrict__ ss1,
                                              float* __restrict__ sd2, float* __restrict__ ss2) {
    __shared__ float a1[Hh * 64];
    __shared__ float a2[Hh * 64];
    int t = threadIdx.x;
    for (int i = t; i < Hh * 64; i += 256) { a1[i] = att1[i]; a2[i] = att2[i]; }
    __syncthreads();
    int n = blockIdx.x * 256 + t;
    if (n >= Nn) return;
    float hv[32];
    const float4* h4 = (const float4*)h + (size_t)n * 8;
#pragma unroll
    for (int i = 0; i < 8; ++i) {
        float4 v = h4[i];
        hv[i * 4 + 0] = v.x; hv[i * 4 + 1] = v.y; hv[i * 4 + 2] = v.z; hv[i * 4 + 3] = v.w;
    }
#pragma unroll
    for (int hh = 0; hh < 8; ++hh) {
        float d1 = 0.f, s1 = 0.f, d2 = 0.f, s2 = 0.f;
#pragma unroll
        for (int d = 0; d < 32; ++d) {
            float x = hv[d];
            d1 += x * a1[hh * 64 + d];
            s1 += x * a1[hh * 64 + 32 + d];
            d2 += x * a2[hh * 64 + d];
            s2 += x * a2[hh * 64 + 32 + d];
        }
        sd1[n * 8 + hh] = d1; ss1[n * 8 + hh] = s1;
        sd2[n * 8 + hh] = d2; ss2[n * 8 + hh] = s2;
    }
}

// K3: scatter edges into padded per-dst slot lists. ei flat = [src[0..E-1], dst[0..E-1]]
__global__ __launch_bounds__(256) void k_scatter(const int* __restrict__ ei, int E,
                                                 int* __restrict__ cnt, int* __restrict__ slots) {
    int e = blockIdx.x * 256 + threadIdx.x;
    if (e >= E) return;
    int s = ei[e];
    int d = ei[E + e];
    int pos = atomicAdd(&cnt[d], 1);
    if (pos < PAD) slots[d * PAD + pos] = s;
}

// K4: GAT layer. One wave per node. lane = hh*8 + sub (head hh, dim-quad sub).
// Pass 1: online max/sum-exp per head (redundantly per lane, all loads broadcast).
// Pass 2: acc += exp(e-m) * h[src][sub*4..]; then /sum, ELU, write Z row.
__global__ __launch_bounds__(256) void k_gat(const float* __restrict__ h,
                                             const float* __restrict__ sdst,
                                             const float* __restrict__ ssrc,
                                             const int* __restrict__ cnt,
                                             const int* __restrict__ slots,
                                             float* __restrict__ Z) {
    int gid = blockIdx.x * 256 + threadIdx.x;
    int n = gid >> 6;
    int lane = gid & 63;
    if (n >= Nn) return;
    int deg = cnt[n]; if (deg > PAD) deg = PAD;
    int hh = lane >> 3;
    int sub = lane & 7;
    float sd = sdst[n * 8 + hh];
    const int* sl = slots + (size_t)n * PAD;

    float m = -3.0e38f, ssum = 0.f;
    for (int i = 0; i < deg; ++i) {
        int s = sl[i];
        float ev = sd + ssrc[s * 8 + hh];
        ev = ev > 0.f ? ev : NEG * ev;
        float nm = fmaxf(m, ev);
        ssum = ssum * __expf(m - nm) + __expf(ev - nm);
        m = nm;
    }
    float4 acc = make_float4(0.f, 0.f, 0.f, 0.f);
    const float4* h4 = (const float4*)h;
    for (int i = 0; i < deg; ++i) {
        int s = sl[i];
        float ev = sd + ssrc[s * 8 + hh];
        ev = ev > 0.f ? ev : NEG * ev;
        float w = __expf(ev - m);
        float4 hv = h4[(size_t)s * 8 + sub];
        acc.x += w * hv.x; acc.y += w * hv.y; acc.z += w * hv.z; acc.w += w * hv.w;
    }
    float inv = 1.f / ssum;
    float4 o;
    o.x = acc.x * inv; o.y = acc.y * inv; o.z = acc.z * inv; o.w = acc.w * inv;
    o.x = o.x > 0.f ? o.x : __expf(o.x) - 1.f;
    o.y = o.y > 0.f ? o.y : __expf(o.y) - 1.f;
    o.z = o.z > 0.f ? o.z : __expf(o.z) - 1.f;
    o.w = o.w > 0.f ? o.w : __expf(o.w) - 1.f;
    ((float4*)Z)[(size_t)n * 64 + lane] = o;
}

// K5: S += sum_n tanh(Z[n] @ fc_w^T + b) . q  for a 64-node tile per block.
// thread t: kq = t&31 (4 k's), ng = t>>5 (8 nodes); 8x4 register block.
__global__ __launch_bounds__(256) void k_score(const float* __restrict__ Z,
                                               const float* __restrict__ fcw,
                                               const float* __restrict__ fcb,
                                               const float* __restrict__ q,
                                               float* __restrict__ Sacc) {
    __shared__ float zt[64 * 256];  // 64 KB
    int t = threadIdx.x;
    float4* zt4 = (float4*)zt;
    const float4* Zg4 = (const float4*)Z;
    size_t gbase = (size_t)blockIdx.x * 4096;
    for (int i = t; i < 4096; i += 256) {
        size_t gi = gbase + i;
        zt4[i] = (gi < (size_t)Nn * 64) ? Zg4[gi] : make_float4(0.f, 0.f, 0.f, 0.f);
    }
    __syncthreads();

    int kq = t & 31;
    int ng = t >> 5;
    float acc[8][4];
#pragma unroll
    for (int nn = 0; nn < 8; ++nn)
#pragma unroll
        for (int kk = 0; kk < 4; ++kk) acc[nn][kk] = 0.f;

    const float4* w4 = (const float4*)fcw;
    for (int j4 = 0; j4 < 64; ++j4) {
        float4 w0 = w4[(kq * 4 + 0) * 64 + j4];
        float4 w1 = w4[(kq * 4 + 1) * 64 + j4];
        float4 w2 = w4[(kq * 4 + 2) * 64 + j4];
        float4 w3 = w4[(kq * 4 + 3) * 64 + j4];
#pragma unroll
        for (int nn = 0; nn < 8; ++nn) {
            float4 zv = zt4[(ng * 8 + nn) * 64 + j4];
            acc[nn][0] += zv.x * w0.x + zv.y * w0.y + zv.z * w0.z + zv.w * w0.w;
            acc[nn][1] += zv.x * w1.x + zv.y * w1.y + zv.z * w1.z + zv.w * w1.w;
            acc[nn][2] += zv.x * w2.x + zv.y * w2.y + zv.z * w2.z + zv.w * w2.w;
            acc[nn][3] += zv.x * w3.x + zv.y * w3.y + zv.z * w3.z + zv.w * w3.w;
        }
    }
    float local = 0.f;
    int nodeBase = blockIdx.x * 64 + ng * 8;
#pragma unroll
    for (int kk = 0; kk < 4; ++kk) {
        int k = kq * 4 + kk;
        float b = fcb[k], qq = q[k];
#pragma unroll
        for (int nn = 0; nn < 8; ++nn) {
            if (nodeBase + nn < Nn) local += tanhf(acc[nn][kk] + b) * qq;
        }
    }
#pragma unroll
    for (int off = 32; off > 0; off >>= 1) local += __shfl_down(local, off);
    if ((t & 63) == 0) atomicAdd(Sacc, local);
}

// K6: V = softmax([S1/N, S2/N])
__global__ void k_final(const float* __restrict__ S, float* __restrict__ V) {
    float s1 = S[0] / (float)Nn;
    float s2 = S[1] / (float)Nn;
    float mx = fmaxf(s1, s2);
    float e1 = __expf(s1 - mx), e2 = __expf(s2 - mx);
    float inv = 1.f / (e1 + e2);
    V[0] = e1 * inv; V[1] = e2 * inv;
}

// K7: out = V0*out + V1*Z2
__global__ __launch_bounds__(256) void k_combine(float* __restrict__ out,
                                                 const float* __restrict__ Z2,
                                                 const float* __restrict__ V) {
    size_t i = (size_t)blockIdx.x * 256 + threadIdx.x;
    float V0 = V[0], V1 = V[1];
    if (i < (size_t)Nn * 64) {
        float4 a = ((float4*)out)[i];
        float4 b = ((const float4*)Z2)[i];
        a.x = V0 * a.x + V1 * b.x;
        a.y = V0 * a.y + V1 * b.y;
        a.z = V0 * a.z + V1 * b.z;
        a.w = V0 * a.w + V1 * b.w;
        ((float4*)out)[i] = a;
    }
}

extern "C" void kernel_launch(void* const* d_in, const int* in_sizes, int n_in,
                              void* d_out, int out_size, void* d_ws, size_t ws_size,
                              hipStream_t stream) {
    const float* x    = (const float*)d_in[0];
    const float* W    = (const float*)d_in[1];
    const float* att1 = (const float*)d_in[2];
    const float* att2 = (const float*)d_in[3];
    const float* fcw  = (const float*)d_in[4];
    const float* fcb  = (const float*)d_in[5];
    const float* q    = (const float*)d_in[6];
    const int*   ei1  = (const int*)d_in[7];
    const int*   ei2  = (const int*)d_in[8];
    int E1 = in_sizes[7] / 2;
    int E2 = in_sizes[8] / 2;
    float* out = (float*)d_out;

    char* ws = (char*)d_ws;
    size_t off = 0;
    auto alloc = [&](size_t bytes) -> char* {
        char* p = ws + off;
        off = (off + bytes + 255) & ~(size_t)255;
        return p;
    };
    float* Z2   = (float*)alloc((size_t)Nn * Cc * 4);
    float* h    = (float*)alloc((size_t)Nn * Dd * 4);
    float* sd1  = (float*)alloc((size_t)Nn * Hh * 4);
    float* ss1  = (float*)alloc((size_t)Nn * Hh * 4);
    float* sd2  = (float*)alloc((size_t)Nn * Hh * 4);
    float* ss2  = (float*)alloc((size_t)Nn * Hh * 4);
    int*   cnt  = (int*)alloc((size_t)2 * Nn * 4);
    float* red  = (float*)alloc(256);
    int*   slt1 = (int*)alloc((size_t)Nn * PAD * 4);
    int*   slt2 = (int*)alloc((size_t)Nn * PAD * 4);
    (void)ws_size; (void)n_in; (void)out_size;

    hipMemsetAsync(cnt, 0, (size_t)2 * Nn * 4, stream);
    hipMemsetAsync(red, 0, 256, stream);

    k_hproj<<<Nn / 32, 256, 0, stream>>>(x, W, h);
    k_satt<<<(Nn + 255) / 256, 256, 0, stream>>>(h, att1, att2, sd1, ss1, sd2, ss2);
    k_scatter<<<(E1 + 255) / 256, 256, 0, stream>>>(ei1, E1, cnt, slt1);
    k_scatter<<<(E2 + 255) / 256, 256, 0, stream>>>(ei2, E2, cnt + Nn, slt2);
    k_gat<<<(Nn * 64) / 256, 256, 0, stream>>>(h, sd1, ss1, cnt, slt1, out);
    k_gat<<<(Nn * 64) / 256, 256, 0, stream>>>(h, sd2, ss2, cnt + Nn, slt2, Z2);
    k_score<<<(Nn + 63) / 64, 256, 0, stream>>>(out, fcw, fcb, q, red + 0);
    k_score<<<(Nn + 63) / 64, 256, 0, stream>>>(Z2, fcw, fcb, q, red + 1);
    k_final<<<1, 1, 0, stream>>>(red, red + 2);
    k_combine<<<(Nn * 64) / 256, 256, 0, stream>>>(out, Z2, red + 2);
}

// Round 2
// 1232.711 us; speedup vs baseline: 1.2181x; 1.2181x over previous
//
#include <hip/hip_runtime.h>
#include <math.h>

#define Nn 100000
#define Cc 256
#define Dd 32
#define Hh 8
#define SEMk 128
#define PAD 32
#define NEG 0.2f

// K0: Wt[j][k] = W[k][j]  (256 x 32 floats) into workspace, run once per call.
__global__ __launch_bounds__(256) void k_wtrans(const float* __restrict__ W,
                                                float* __restrict__ Wt) {
    int i = blockIdx.x * 256 + threadIdx.x;  // 8192 floats
    if (i < Dd * Cc) {
        int j = i >> 5, k = i & 31;
        Wt[i] = W[k * Cc + j];
    }
}

// K1 (fused): h = x @ W^T, plus per-node attention projections for both layers.
// Block = 256 threads = 32 nodes x 8 quads. LDS-staged x tile + transposed W.
__global__ __launch_bounds__(256) void k_hproj(const float* __restrict__ x,
                                               const float* __restrict__ Wt,
                                               const float* __restrict__ att1,
                                               const float* __restrict__ att2,
                                               float* __restrict__ h,
                                               float* __restrict__ sd1, float* __restrict__ ss1,
                                               float* __restrict__ sd2, float* __restrict__ ss2) {
    __shared__ float4 xs[32 * 65];     // 32 rows x 64 f4, +1 f4 row pad (bank stride 4)
    __shared__ float  wt[256 * 36];    // wt[j][k], row stride 36 floats
    __shared__ float4 hs[32 * 9];      // h tile, row stride 9 f4 (36 floats)
    __shared__ float  a1[8 * 68];      // att rows padded to 68 floats
    __shared__ float  a2[8 * 68];

    int t = threadIdx.x;
    int nb = blockIdx.x * 32;

    // stage x tile: 2048 f4, fully coalesced
    const float4* xg = (const float4*)x + (size_t)nb * 64;
#pragma unroll
    for (int it = 0; it < 8; ++it) {
        int i = t + it * 256;
        xs[(i >> 6) * 65 + (i & 63)] = xg[i];
    }
    // stage Wt: 2048 f4
    const float4* wg = (const float4*)Wt;
#pragma unroll
    for (int it = 0; it < 8; ++it) {
        int i = t + it * 256;                       // j = i>>3, k4 = i&7
        *(float4*)&wt[(i >> 3) * 36 + (i & 7) * 4] = wg[i];
    }
    // stage att (512 floats each)
#pragma unroll
    for (int it = 0; it < 2; ++it) {
        int i = t + it * 256;
        a1[(i >> 6) * 68 + (i & 63)] = att1[i];
        a2[(i >> 6) * 68 + (i & 63)] = att2[i];
    }
    __syncthreads();

    int nl = t >> 3;   // node in tile
    int dq = t & 7;    // output k-quad
    float4 acc = make_float4(0.f, 0.f, 0.f, 0.f);
    const float4* xr = &xs[nl * 65];
#pragma unroll 4
    for (int j4 = 0; j4 < 64; ++j4) {
        float4 xv = xr[j4];
        float4 w0 = *(const float4*)&wt[(j4 * 4 + 0) * 36 + dq * 4];
        float4 w1 = *(const float4*)&wt[(j4 * 4 + 1) * 36 + dq * 4];
        float4 w2 = *(const float4*)&wt[(j4 * 4 + 2) * 36 + dq * 4];
        float4 w3 = *(const float4*)&wt[(j4 * 4 + 3) * 36 + dq * 4];
        acc.x += xv.x * w0.x + xv.y * w1.x + xv.z * w2.x + xv.w * w3.x;
        acc.y += xv.x * w0.y + xv.y * w1.y + xv.z * w2.y + xv.w * w3.y;
        acc.z += xv.x * w0.z + xv.y * w1.z + xv.z * w2.z + xv.w * w3.z;
        acc.w += xv.x * w0.w + xv.y * w1.w + xv.z * w2.w + xv.w * w3.w;
    }
    ((float4*)h)[(size_t)(nb + nl) * 8 + dq] = acc;
    hs[nl * 9 + dq] = acc;
    __syncthreads();

    // fused satt: thread = (node nl2, head hh)
    int nl2 = t >> 3;
    int hh = t & 7;
    float d1 = 0.f, s1 = 0.f, d2 = 0.f, s2 = 0.f;
#pragma unroll
    for (int d4 = 0; d4 < 8; ++d4) {
        float4 hv = hs[nl2 * 9 + d4];
        float4 ad1 = *(const float4*)&a1[hh * 68 + d4 * 4];
        float4 as1 = *(const float4*)&a1[hh * 68 + 32 + d4 * 4];
        float4 ad2 = *(const float4*)&a2[hh * 68 + d4 * 4];
        float4 as2 = *(const float4*)&a2[hh * 68 + 32 + d4 * 4];
        d1 += hv.x * ad1.x + hv.y * ad1.y + hv.z * ad1.z + hv.w * ad1.w;
        s1 += hv.x * as1.x + hv.y * as1.y + hv.z * as1.z + hv.w * as1.w;
        d2 += hv.x * ad2.x + hv.y * ad2.y + hv.z * ad2.z + hv.w * ad2.w;
        s2 += hv.x * as2.x + hv.y * as2.y + hv.z * as2.z + hv.w * as2.w;
    }
    int n = nb + nl2;
    sd1[n * 8 + hh] = d1; ss1[n * 8 + hh] = s1;
    sd2[n * 8 + hh] = d2; ss2[n * 8 + hh] = s2;
}

// K3: scatter edges into padded per-dst slot lists. ei flat = [src[..], dst[..]]
__global__ __launch_bounds__(256) void k_scatter(const int* __restrict__ ei, int E,
                                                 int* __restrict__ cnt, int* __restrict__ slots) {
    int e = blockIdx.x * 256 + threadIdx.x;
    if (e >= E) return;
    int s = ei[e];
    int d = ei[E + e];
    int pos = atomicAdd(&cnt[d], 1);
    if (pos < PAD) slots[d * PAD + pos] = s;
}

// K4: GAT layer, single-pass (softmax shift-invariant; |e|~O(4) so raw exp safe).
// One wave per node. lane = hh*8 + sub. Slot list preloaded via one coalesced
// read + shfl — no per-edge dependent slot load.
__global__ __launch_bounds__(256) void k_gat(const float* __restrict__ h,
                                             const float* __restrict__ sdst,
                                             const float* __restrict__ ssrc,
                                             const int* __restrict__ cnt,
                                             const int* __restrict__ slots,
                                             float* __restrict__ Z) {
    int gid = blockIdx.x * 256 + threadIdx.x;
    int n = gid >> 6;
    int lane = gid & 63;
    if (n >= Nn) return;
    int deg = cnt[n]; if (deg > PAD) deg = PAD;
    int hh = lane >> 3;
    int sub = lane & 7;
    float sd = sdst[n * 8 + hh];
    int sval = slots[n * PAD + (lane & 31)];   // whole slot row in-wave

    float ssum = 0.f;
    float4 acc = make_float4(0.f, 0.f, 0.f, 0.f);
    const float4* h4 = (const float4*)h;
#pragma unroll 2
    for (int i = 0; i < deg; ++i) {
        int s = __shfl(sval, i);
        float ev = sd + ssrc[s * 8 + hh];
        ev = ev > 0.f ? ev : NEG * ev;
        float w = __expf(ev);
        float4 hv = h4[(size_t)s * 8 + sub];
        acc.x += w * hv.x; acc.y += w * hv.y; acc.z += w * hv.z; acc.w += w * hv.w;
        ssum += w;
    }
    float inv = 1.f / ssum;
    float4 o;
    o.x = acc.x * inv; o.y = acc.y * inv; o.z = acc.z * inv; o.w = acc.w * inv;
    o.x = o.x > 0.f ? o.x : __expf(o.x) - 1.f;
    o.y = o.y > 0.f ? o.y : __expf(o.y) - 1.f;
    o.z = o.z > 0.f ? o.z : __expf(o.z) - 1.f;
    o.w = o.w > 0.f ? o.w : __expf(o.w) - 1.f;
    ((float4*)Z)[(size_t)n * 64 + lane] = o;
}

__device__ __forceinline__ float fast_tanh(float x) {
    return 1.f - 2.f / (1.f + __expf(2.f * x));
}

// K5: S += sum_n tanh(Z[n] @ fc_w^T + b) . q   — 32-node tile (32 KB LDS).
// thread t: kq = t&31 (4 ks), ng = t>>5 (4 nodes); 4x4 register block.
__global__ __launch_bounds__(256) void k_score(const float* __restrict__ Z,
                                               const float* __restrict__ fcw,
                                               const float* __restrict__ fcb,
                                               const float* __restrict__ q,
                                               float* __restrict__ Sacc) {
    __shared__ float4 zt4[32 * 64];  // 32 KB
    int t = threadIdx.x;
    const float4* Zg4 = (const float4*)Z;
    size_t gbase = (size_t)blockIdx.x * 2048;
#pragma unroll
    for (int it = 0; it < 8; ++it) zt4[t + it * 256] = Zg4[gbase + t + it * 256];
    __syncthreads();

    int kq = t & 31;
    int ng = t >> 5;
    float acc[4][4];
#pragma unroll
    for (int nn = 0; nn < 4; ++nn)
#pragma unroll
        for (int kk = 0; kk < 4; ++kk) acc[nn][kk] = 0.f;

    const float4* w4 = (const float4*)fcw;
    for (int j4 = 0; j4 < 64; ++j4) {
        float4 w0 = w4[(kq * 4 + 0) * 64 + j4];
        float4 w1 = w4[(kq * 4 + 1) * 64 + j4];
        float4 w2 = w4[(kq * 4 + 2) * 64 + j4];
        float4 w3 = w4[(kq * 4 + 3) * 64 + j4];
#pragma unroll
        for (int nn = 0; nn < 4; ++nn) {
            float4 zv = zt4[(ng * 4 + nn) * 64 + j4];
            acc[nn][0] += zv.x * w0.x + zv.y * w0.y + zv.z * w0.z + zv.w * w0.w;
            acc[nn][1] += zv.x * w1.x + zv.y * w1.y + zv.z * w1.z + zv.w * w1.w;
            acc[nn][2] += zv.x * w2.x + zv.y * w2.y + zv.z * w2.z + zv.w * w2.w;
            acc[nn][3] += zv.x * w3.x + zv.y * w3.y + zv.z * w3.z + zv.w * w3.w;
        }
    }
    float local = 0.f;
#pragma unroll
    for (int kk = 0; kk < 4; ++kk) {
        int k = kq * 4 + kk;
        float b = fcb[k], qq = q[k];
#pragma unroll
        for (int nn = 0; nn < 4; ++nn) local += fast_tanh(acc[nn][kk] + b) * qq;
    }
#pragma unroll
    for (int off = 32; off > 0; off >>= 1) local += __shfl_down(local, off);
    if ((t & 63) == 0) atomicAdd(Sacc, local);
}

// K6: V = softmax([S1/N, S2/N])
__global__ void k_final(const float* __restrict__ S, float* __restrict__ V) {
    float s1 = S[0] / (float)Nn;
    float s2 = S[1] / (float)Nn;
    float mx = fmaxf(s1, s2);
    float e1 = __expf(s1 - mx), e2 = __expf(s2 - mx);
    float inv = 1.f / (e1 + e2);
    V[0] = e1 * inv; V[1] = e2 * inv;
}

// K7: out = V0*out + V1*Z2
__global__ __launch_bounds__(256) void k_combine(float* __restrict__ out,
                                                 const float* __restrict__ Z2,
                                                 const float* __restrict__ V) {
    size_t i = (size_t)blockIdx.x * 256 + threadIdx.x;
    float V0 = V[0], V1 = V[1];
    if (i < (size_t)Nn * 64) {
        float4 a = ((float4*)out)[i];
        float4 b = ((const float4*)Z2)[i];
        a.x = V0 * a.x + V1 * b.x;
        a.y = V0 * a.y + V1 * b.y;
        a.z = V0 * a.z + V1 * b.z;
        a.w = V0 * a.w + V1 * b.w;
        ((float4*)out)[i] = a;
    }
}

extern "C" void kernel_launch(void* const* d_in, const int* in_sizes, int n_in,
                              void* d_out, int out_size, void* d_ws, size_t ws_size,
                              hipStream_t stream) {
    const float* x    = (const float*)d_in[0];
    const float* W    = (const float*)d_in[1];
    const float* att1 = (const float*)d_in[2];
    const float* att2 = (const float*)d_in[3];
    const float* fcw  = (const float*)d_in[4];
    const float* fcb  = (const float*)d_in[5];
    const float* q    = (const float*)d_in[6];
    const int*   ei1  = (const int*)d_in[7];
    const int*   ei2  = (const int*)d_in[8];
    int E1 = in_sizes[7] / 2;
    int E2 = in_sizes[8] / 2;
    float* out = (float*)d_out;

    char* ws = (char*)d_ws;
    size_t off = 0;
    auto alloc = [&](size_t bytes) -> char* {
        char* p = ws + off;
        off = (off + bytes + 255) & ~(size_t)255;
        return p;
    };
    float* Z2   = (float*)alloc((size_t)Nn * Cc * 4);
    float* h    = (float*)alloc((size_t)Nn * Dd * 4);
    float* sd1  = (float*)alloc((size_t)Nn * Hh * 4);
    float* ss1  = (float*)alloc((size_t)Nn * Hh * 4);
    float* sd2  = (float*)alloc((size_t)Nn * Hh * 4);
    float* ss2  = (float*)alloc((size_t)Nn * Hh * 4);
    int*   cnt  = (int*)alloc((size_t)2 * Nn * 4);
    float* red  = (float*)alloc(256);
    float* Wt   = (float*)alloc((size_t)Dd * Cc * 4);
    int*   slt1 = (int*)alloc((size_t)Nn * PAD * 4);
    int*   slt2 = (int*)alloc((size_t)Nn * PAD * 4);
    (void)ws_size; (void)n_in; (void)out_size;

    hipMemsetAsync(cnt, 0, (size_t)2 * Nn * 4, stream);
    hipMemsetAsync(red, 0, 256, stream);

    k_wtrans<<<(Dd * Cc + 255) / 256, 256, 0, stream>>>(W, Wt);
    k_hproj<<<Nn / 32, 256, 0, stream>>>(x, Wt, att1, att2, h, sd1, ss1, sd2, ss2);
    k_scatter<<<(E1 + 255) / 256, 256, 0, stream>>>(ei1, E1, cnt, slt1);
    k_scatter<<<(E2 + 255) / 256, 256, 0, stream>>>(ei2, E2, cnt + Nn, slt2);
    k_gat<<<(Nn * 64) / 256, 256, 0, stream>>>(h, sd1, ss1, cnt, slt1, out);
    k_gat<<<(Nn * 64) / 256, 256, 0, stream>>>(h, sd2, ss2, cnt + Nn, slt2, Z2);
    k_score<<<(Nn + 31) / 32, 256, 0, stream>>>(out, fcw, fcb, q, red + 0);
    k_score<<<(Nn + 31) / 32, 256, 0, stream>>>(Z2, fcw, fcb, q, red + 1);
    k_final<<<1, 1, 0, stream>>>(red, red + 2);
    k_combine<<<(Nn * 64) / 256, 256, 0, stream>>>(out, Z2, red + 2);
}

// Round 3
// 738.230 us; speedup vs baseline: 2.0340x; 1.6698x over previous
//
#include <hip/hip_runtime.h>
#include <math.h>

#define Nn 100000
#define Cc 256
#define Dd 32
#define Hh 8
#define SEMk 128
#define PAD 32
#define NEG 0.2f

typedef __attribute__((ext_vector_type(8))) short bf16x8;
typedef __attribute__((ext_vector_type(4))) float f32x4;

__device__ __forceinline__ short f2bf(float f) {
    unsigned u = __float_as_uint(f);
    u = (u + 0x7FFF + ((u >> 16) & 1)) >> 16;   // round-to-nearest-even
    return (short)u;
}

// K0a: Wt[j][k] = W[k][j]  (256 x 32 floats)
__global__ __launch_bounds__(256) void k_wtrans(const float* __restrict__ W,
                                                float* __restrict__ Wt) {
    int i = blockIdx.x * 256 + threadIdx.x;
    if (i < Dd * Cc) {
        int j = i >> 5, k = i & 31;
        Wt[i] = W[k * Cc + j];
    }
}

// K0b: fcwb = bf16(fc_w)  (128 x 256)
__global__ __launch_bounds__(256) void k_fcwb(const float* __restrict__ fcw,
                                              short* __restrict__ fcwb) {
    int i = blockIdx.x * 256 + threadIdx.x;
    if (i < SEMk * Cc) fcwb[i] = f2bf(fcw[i]);
}

// K1 (fused): h = x @ W^T, plus per-node attention projections for both layers.
__global__ __launch_bounds__(256) void k_hproj(const float* __restrict__ x,
                                               const float* __restrict__ Wt,
                                               const float* __restrict__ att1,
                                               const float* __restrict__ att2,
                                               float* __restrict__ h,
                                               float* __restrict__ sd1, float* __restrict__ ss1,
                                               float* __restrict__ sd2, float* __restrict__ ss2) {
    __shared__ float4 xs[32 * 65];
    __shared__ float  wt[256 * 36];
    __shared__ float4 hs[32 * 9];
    __shared__ float  a1[8 * 68];
    __shared__ float  a2[8 * 68];

    int t = threadIdx.x;
    int nb = blockIdx.x * 32;

    const float4* xg = (const float4*)x + (size_t)nb * 64;
#pragma unroll
    for (int it = 0; it < 8; ++it) {
        int i = t + it * 256;
        xs[(i >> 6) * 65 + (i & 63)] = xg[i];
    }
    const float4* wg = (const float4*)Wt;
#pragma unroll
    for (int it = 0; it < 8; ++it) {
        int i = t + it * 256;
        *(float4*)&wt[(i >> 3) * 36 + (i & 7) * 4] = wg[i];
    }
#pragma unroll
    for (int it = 0; it < 2; ++it) {
        int i = t + it * 256;
        a1[(i >> 6) * 68 + (i & 63)] = att1[i];
        a2[(i >> 6) * 68 + (i & 63)] = att2[i];
    }
    __syncthreads();

    int nl = t >> 3;
    int dq = t & 7;
    float4 acc = make_float4(0.f, 0.f, 0.f, 0.f);
    const float4* xr = &xs[nl * 65];
#pragma unroll 4
    for (int j4 = 0; j4 < 64; ++j4) {
        float4 xv = xr[j4];
        float4 w0 = *(const float4*)&wt[(j4 * 4 + 0) * 36 + dq * 4];
        float4 w1 = *(const float4*)&wt[(j4 * 4 + 1) * 36 + dq * 4];
        float4 w2 = *(const float4*)&wt[(j4 * 4 + 2) * 36 + dq * 4];
        float4 w3 = *(const float4*)&wt[(j4 * 4 + 3) * 36 + dq * 4];
        acc.x += xv.x * w0.x + xv.y * w1.x + xv.z * w2.x + xv.w * w3.x;
        acc.y += xv.x * w0.y + xv.y * w1.y + xv.z * w2.y + xv.w * w3.y;
        acc.z += xv.x * w0.z + xv.y * w1.z + xv.z * w2.z + xv.w * w3.z;
        acc.w += xv.x * w0.w + xv.y * w1.w + xv.z * w2.w + xv.w * w3.w;
    }
    ((float4*)h)[(size_t)(nb + nl) * 8 + dq] = acc;
    hs[nl * 9 + dq] = acc;
    __syncthreads();

    int nl2 = t >> 3;
    int hh = t & 7;
    float d1 = 0.f, s1 = 0.f, d2 = 0.f, s2 = 0.f;
#pragma unroll
    for (int d4 = 0; d4 < 8; ++d4) {
        float4 hv = hs[nl2 * 9 + d4];
        float4 ad1 = *(const float4*)&a1[hh * 68 + d4 * 4];
        float4 as1 = *(const float4*)&a1[hh * 68 + 32 + d4 * 4];
        float4 ad2 = *(const float4*)&a2[hh * 68 + d4 * 4];
        float4 as2 = *(const float4*)&a2[hh * 68 + 32 + d4 * 4];
        d1 += hv.x * ad1.x + hv.y * ad1.y + hv.z * ad1.z + hv.w * ad1.w;
        s1 += hv.x * as1.x + hv.y * as1.y + hv.z * as1.z + hv.w * as1.w;
        d2 += hv.x * ad2.x + hv.y * ad2.y + hv.z * ad2.z + hv.w * ad2.w;
        s2 += hv.x * as2.x + hv.y * as2.y + hv.z * as2.z + hv.w * as2.w;
    }
    int n = nb + nl2;
    sd1[n * 8 + hh] = d1; ss1[n * 8 + hh] = s1;
    sd2[n * 8 + hh] = d2; ss2[n * 8 + hh] = s2;
}

// K3: scatter edges into padded per-dst slot lists.
__global__ __launch_bounds__(256) void k_scatter(const int* __restrict__ ei, int E,
                                                 int* __restrict__ cnt, int* __restrict__ slots) {
    int e = blockIdx.x * 256 + threadIdx.x;
    if (e >= E) return;
    int s = ei[e];
    int d = ei[E + e];
    int pos = atomicAdd(&cnt[d], 1);
    if (pos < PAD) slots[d * PAD + pos] = s;
}

// K4: GAT layer, single-pass softmax; one wave per node.
__global__ __launch_bounds__(256) void k_gat(const float* __restrict__ h,
                                             const float* __restrict__ sdst,
                                             const float* __restrict__ ssrc,
                                             const int* __restrict__ cnt,
                                             const int* __restrict__ slots,
                                             float* __restrict__ Z) {
    int gid = blockIdx.x * 256 + threadIdx.x;
    int n = gid >> 6;
    int lane = gid & 63;
    if (n >= Nn) return;
    int deg = cnt[n]; if (deg > PAD) deg = PAD;
    int hh = lane >> 3;
    int sub = lane & 7;
    float sd = sdst[n * 8 + hh];
    int sval = slots[n * PAD + (lane & 31)];

    float ssum = 0.f;
    float4 acc = make_float4(0.f, 0.f, 0.f, 0.f);
    const float4* h4 = (const float4*)h;
#pragma unroll 2
    for (int i = 0; i < deg; ++i) {
        int s = __shfl(sval, i);
        float ev = sd + ssrc[s * 8 + hh];
        ev = ev > 0.f ? ev : NEG * ev;
        float w = __expf(ev);
        float4 hv = h4[(size_t)s * 8 + sub];
        acc.x += w * hv.x; acc.y += w * hv.y; acc.z += w * hv.z; acc.w += w * hv.w;
        ssum += w;
    }
    float inv = 1.f / ssum;
    float4 o;
    o.x = acc.x * inv; o.y = acc.y * inv; o.z = acc.z * inv; o.w = acc.w * inv;
    o.x = o.x > 0.f ? o.x : __expf(o.x) - 1.f;
    o.y = o.y > 0.f ? o.y : __expf(o.y) - 1.f;
    o.z = o.z > 0.f ? o.z : __expf(o.z) - 1.f;
    o.w = o.w > 0.f ? o.w : __expf(o.w) - 1.f;
    ((float4*)Z)[(size_t)n * 64 + lane] = o;
}

__device__ __forceinline__ float fast_tanh(float x) {
    return 1.f - 2.f / (1.f + __expf(2.f * x));
}

// K5: MFMA score. One wave = 16 nodes x 128 sem dims. C = Z(bf16) . fcwb^T.
// A-frag: lane m=lane&15 (node), k = quad*8..+7 contiguous (fp32->bf16 on the fly).
// B-frag: lane n=lane&15 (sem k), same k block (fcwb row-major [n][k], B^T pattern).
// D: col=lane&15 (sem), row=quad*4+reg (node). No LDS, no barriers.
__global__ __launch_bounds__(256) void k_score(const float* __restrict__ Z,
                                               const short* __restrict__ fcwb,
                                               const float* __restrict__ fcb,
                                               const float* __restrict__ q,
                                               float* __restrict__ Sacc) {
    int t = threadIdx.x;
    int lane = t & 63;
    int wid = t >> 6;
    int wave = blockIdx.x * 4 + wid;
    if (wave >= Nn / 16) return;       // Nn divisible by 16
    int nodebase = wave * 16;
    int col = lane & 15;
    int quad = lane >> 4;

    f32x4 acc[8];
#pragma unroll
    for (int tt = 0; tt < 8; ++tt) { acc[tt][0] = 0.f; acc[tt][1] = 0.f; acc[tt][2] = 0.f; acc[tt][3] = 0.f; }

    const float4* Zg = (const float4*)(Z + (size_t)(nodebase + col) * Cc);
#pragma unroll
    for (int ks = 0; ks < 8; ++ks) {
        // A fragment: 8 fp32 -> bf16
        float4 lo = Zg[ks * 8 + quad * 2 + 0];
        float4 hi = Zg[ks * 8 + quad * 2 + 1];
        bf16x8 a;
        a[0] = f2bf(lo.x); a[1] = f2bf(lo.y); a[2] = f2bf(lo.z); a[3] = f2bf(lo.w);
        a[4] = f2bf(hi.x); a[5] = f2bf(hi.y); a[6] = f2bf(hi.z); a[7] = f2bf(hi.w);
#pragma unroll
        for (int tt = 0; tt < 8; ++tt) {
            bf16x8 b = *(const bf16x8*)(fcwb + (size_t)(tt * 16 + col) * Cc + ks * 32 + quad * 8);
            acc[tt] = __builtin_amdgcn_mfma_f32_16x16x32_bf16(a, b, acc[tt], 0, 0, 0);
        }
    }

    float local = 0.f;
#pragma unroll
    for (int tt = 0; tt < 8; ++tt) {
        int n = tt * 16 + col;
        float b = fcb[n], qq = q[n];
#pragma unroll
        for (int r = 0; r < 4; ++r) local += fast_tanh(acc[tt][r] + b) * qq;
    }
#pragma unroll
    for (int off = 32; off > 0; off >>= 1) local += __shfl_down(local, off);
    if (lane == 0) atomicAdd(Sacc, local);
}

// K7: out = V0*out + V1*Z2, V = softmax([S1/N, S2/N]) computed inline.
__global__ __launch_bounds__(256) void k_combine(float* __restrict__ out,
                                                 const float* __restrict__ Z2,
                                                 const float* __restrict__ S) {
    float s1 = S[0] * (1.f / (float)Nn);
    float s2 = S[1] * (1.f / (float)Nn);
    float mx = fmaxf(s1, s2);
    float e1 = __expf(s1 - mx), e2 = __expf(s2 - mx);
    float inv = 1.f / (e1 + e2);
    float V0 = e1 * inv, V1 = e2 * inv;
    size_t i = (size_t)blockIdx.x * 256 + threadIdx.x;
    if (i < (size_t)Nn * 64) {
        float4 a = ((float4*)out)[i];
        float4 b = ((const float4*)Z2)[i];
        a.x = V0 * a.x + V1 * b.x;
        a.y = V0 * a.y + V1 * b.y;
        a.z = V0 * a.z + V1 * b.z;
        a.w = V0 * a.w + V1 * b.w;
        ((float4*)out)[i] = a;
    }
}

extern "C" void kernel_launch(void* const* d_in, const int* in_sizes, int n_in,
                              void* d_out, int out_size, void* d_ws, size_t ws_size,
                              hipStream_t stream) {
    const float* x    = (const float*)d_in[0];
    const float* W    = (const float*)d_in[1];
    const float* att1 = (const float*)d_in[2];
    const float* att2 = (const float*)d_in[3];
    const float* fcw  = (const float*)d_in[4];
    const float* fcb  = (const float*)d_in[5];
    const float* q    = (const float*)d_in[6];
    const int*   ei1  = (const int*)d_in[7];
    const int*   ei2  = (const int*)d_in[8];
    int E1 = in_sizes[7] / 2;
    int E2 = in_sizes[8] / 2;
    float* out = (float*)d_out;

    char* ws = (char*)d_ws;
    size_t off = 0;
    auto alloc = [&](size_t bytes) -> char* {
        char* p = ws + off;
        off = (off + bytes + 255) & ~(size_t)255;
        return p;
    };
    float* Z2   = (float*)alloc((size_t)Nn * Cc * 4);
    float* h    = (float*)alloc((size_t)Nn * Dd * 4);
    float* sd1  = (float*)alloc((size_t)Nn * Hh * 4);
    float* ss1  = (float*)alloc((size_t)Nn * Hh * 4);
    float* sd2  = (float*)alloc((size_t)Nn * Hh * 4);
    float* ss2  = (float*)alloc((size_t)Nn * Hh * 4);
    int*   cnt  = (int*)alloc((size_t)2 * Nn * 4);
    float* red  = (float*)alloc(256);
    float* Wt   = (float*)alloc((size_t)Dd * Cc * 4);
    short* fcwb = (short*)alloc((size_t)SEMk * Cc * 2);
    int*   slt1 = (int*)alloc((size_t)Nn * PAD * 4);
    int*   slt2 = (int*)alloc((size_t)Nn * PAD * 4);
    (void)ws_size; (void)n_in; (void)out_size;

    hipMemsetAsync(cnt, 0, (size_t)2 * Nn * 4, stream);
    hipMemsetAsync(red, 0, 256, stream);

    k_wtrans<<<(Dd * Cc + 255) / 256, 256, 0, stream>>>(W, Wt);
    k_fcwb<<<(SEMk * Cc + 255) / 256, 256, 0, stream>>>(fcw, fcwb);
    k_hproj<<<Nn / 32, 256, 0, stream>>>(x, Wt, att1, att2, h, sd1, ss1, sd2, ss2);
    k_scatter<<<(E1 + 255) / 256, 256, 0, stream>>>(ei1, E1, cnt, slt1);
    k_scatter<<<(E2 + 255) / 256, 256, 0, stream>>>(ei2, E2, cnt + Nn, slt2);
    k_gat<<<(Nn * 64) / 256, 256, 0, stream>>>(h, sd1, ss1, cnt, slt1, out);
    k_gat<<<(Nn * 64) / 256, 256, 0, stream>>>(h, sd2, ss2, cnt + Nn, slt2, Z2);
    int nwaves = Nn / 16;                     // 6250
    k_score<<<(nwaves + 3) / 4, 256, 0, stream>>>(out, fcwb, fcb, q, red + 0);
    k_score<<<(nwaves + 3) / 4, 256, 0, stream>>>(Z2, fcwb, fcb, q, red + 1);
    k_combine<<<(Nn * 64) / 256, 256, 0, stream>>>(out, Z2, red);
}

// Round 4
// 604.813 us; speedup vs baseline: 2.4827x; 1.2206x over previous
//
#include <hip/hip_runtime.h>
#include <math.h>

#define Nn 100000
#define Cc 256
#define Dd 32
#define Hh 8
#define SEMk 128
#define PAD 32
#define NEG 0.2f

typedef __attribute__((ext_vector_type(8))) short bf16x8;
typedef __attribute__((ext_vector_type(4))) short s16x4;
typedef __attribute__((ext_vector_type(4))) float f32x4;

__device__ __forceinline__ short f2bf(float f) {
    unsigned u = __float_as_uint(f);
    u = (u + 0x7FFF + ((u >> 16) & 1)) >> 16;   // round-to-nearest-even
    return (short)u;
}

// K0a: Wt[j][k] = W[k][j]  (256 x 32 floats)
__global__ __launch_bounds__(256) void k_wtrans(const float* __restrict__ W,
                                                float* __restrict__ Wt) {
    int i = blockIdx.x * 256 + threadIdx.x;
    if (i < Dd * Cc) {
        int j = i >> 5, k = i & 31;
        Wt[i] = W[k * Cc + j];
    }
}

// K0b: fcwb = bf16(fc_w)  (128 x 256)
__global__ __launch_bounds__(256) void k_fcwb(const float* __restrict__ fcw,
                                              short* __restrict__ fcwb) {
    int i = blockIdx.x * 256 + threadIdx.x;
    if (i < SEMk * Cc) fcwb[i] = f2bf(fcw[i]);
}

// K1 (fused): h = x @ W^T, plus per-node attention projections for both layers.
__global__ __launch_bounds__(256) void k_hproj(const float* __restrict__ x,
                                               const float* __restrict__ Wt,
                                               const float* __restrict__ att1,
                                               const float* __restrict__ att2,
                                               float* __restrict__ h,
                                               float* __restrict__ sd1, float* __restrict__ ss1,
                                               float* __restrict__ sd2, float* __restrict__ ss2) {
    __shared__ float4 xs[32 * 65];
    __shared__ float  wt[256 * 36];
    __shared__ float4 hs[32 * 9];
    __shared__ float  a1[8 * 68];
    __shared__ float  a2[8 * 68];

    int t = threadIdx.x;
    int nb = blockIdx.x * 32;

    const float4* xg = (const float4*)x + (size_t)nb * 64;
#pragma unroll
    for (int it = 0; it < 8; ++it) {
        int i = t + it * 256;
        xs[(i >> 6) * 65 + (i & 63)] = xg[i];
    }
    const float4* wg = (const float4*)Wt;
#pragma unroll
    for (int it = 0; it < 8; ++it) {
        int i = t + it * 256;
        *(float4*)&wt[(i >> 3) * 36 + (i & 7) * 4] = wg[i];
    }
#pragma unroll
    for (int it = 0; it < 2; ++it) {
        int i = t + it * 256;
        a1[(i >> 6) * 68 + (i & 63)] = att1[i];
        a2[(i >> 6) * 68 + (i & 63)] = att2[i];
    }
    __syncthreads();

    int nl = t >> 3;
    int dq = t & 7;
    float4 acc = make_float4(0.f, 0.f, 0.f, 0.f);
    const float4* xr = &xs[nl * 65];
#pragma unroll 4
    for (int j4 = 0; j4 < 64; ++j4) {
        float4 xv = xr[j4];
        float4 w0 = *(const float4*)&wt[(j4 * 4 + 0) * 36 + dq * 4];
        float4 w1 = *(const float4*)&wt[(j4 * 4 + 1) * 36 + dq * 4];
        float4 w2 = *(const float4*)&wt[(j4 * 4 + 2) * 36 + dq * 4];
        float4 w3 = *(const float4*)&wt[(j4 * 4 + 3) * 36 + dq * 4];
        acc.x += xv.x * w0.x + xv.y * w1.x + xv.z * w2.x + xv.w * w3.x;
        acc.y += xv.x * w0.y + xv.y * w1.y + xv.z * w2.y + xv.w * w3.y;
        acc.z += xv.x * w0.z + xv.y * w1.z + xv.z * w2.z + xv.w * w3.z;
        acc.w += xv.x * w0.w + xv.y * w1.w + xv.z * w2.w + xv.w * w3.w;
    }
    ((float4*)h)[(size_t)(nb + nl) * 8 + dq] = acc;
    hs[nl * 9 + dq] = acc;
    __syncthreads();

    int nl2 = t >> 3;
    int hh = t & 7;
    float d1 = 0.f, s1 = 0.f, d2 = 0.f, s2 = 0.f;
#pragma unroll
    for (int d4 = 0; d4 < 8; ++d4) {
        float4 hv = hs[nl2 * 9 + d4];
        float4 ad1 = *(const float4*)&a1[hh * 68 + d4 * 4];
        float4 as1 = *(const float4*)&a1[hh * 68 + 32 + d4 * 4];
        float4 ad2 = *(const float4*)&a2[hh * 68 + d4 * 4];
        float4 as2 = *(const float4*)&a2[hh * 68 + 32 + d4 * 4];
        d1 += hv.x * ad1.x + hv.y * ad1.y + hv.z * ad1.z + hv.w * ad1.w;
        s1 += hv.x * as1.x + hv.y * as1.y + hv.z * as1.z + hv.w * as1.w;
        d2 += hv.x * ad2.x + hv.y * ad2.y + hv.z * ad2.z + hv.w * ad2.w;
        s2 += hv.x * as2.x + hv.y * as2.y + hv.z * as2.z + hv.w * as2.w;
    }
    int n = nb + nl2;
    sd1[n * 8 + hh] = d1; ss1[n * 8 + hh] = s1;
    sd2[n * 8 + hh] = d2; ss2[n * 8 + hh] = s2;
}

// K3: scatter edges into padded per-dst slot lists.
__global__ __launch_bounds__(256) void k_scatter(const int* __restrict__ ei, int E,
                                                 int* __restrict__ cnt, int* __restrict__ slots) {
    int e = blockIdx.x * 256 + threadIdx.x;
    if (e >= E) return;
    int s = ei[e];
    int d = ei[E + e];
    int pos = atomicAdd(&cnt[d], 1);
    if (pos < PAD) slots[d * PAD + pos] = s;
}

// K4: GAT layer, single-pass softmax; one wave per node.
__global__ __launch_bounds__(256) void k_gat(const float* __restrict__ h,
                                             const float* __restrict__ sdst,
                                             const float* __restrict__ ssrc,
                                             const int* __restrict__ cnt,
                                             const int* __restrict__ slots,
                                             float* __restrict__ Z) {
    int gid = blockIdx.x * 256 + threadIdx.x;
    int n = gid >> 6;
    int lane = gid & 63;
    if (n >= Nn) return;
    int deg = cnt[n]; if (deg > PAD) deg = PAD;
    int hh = lane >> 3;
    int sub = lane & 7;
    float sd = sdst[n * 8 + hh];
    int sval = slots[n * PAD + (lane & 31)];

    float ssum = 0.f;
    float4 acc = make_float4(0.f, 0.f, 0.f, 0.f);
    const float4* h4 = (const float4*)h;
#pragma unroll 2
    for (int i = 0; i < deg; ++i) {
        int s = __shfl(sval, i);
        float ev = sd + ssrc[s * 8 + hh];
        ev = ev > 0.f ? ev : NEG * ev;
        float w = __expf(ev);
        float4 hv = h4[(size_t)s * 8 + sub];
        acc.x += w * hv.x; acc.y += w * hv.y; acc.z += w * hv.z; acc.w += w * hv.w;
        ssum += w;
    }
    float inv = 1.f / ssum;
    float4 o;
    o.x = acc.x * inv; o.y = acc.y * inv; o.z = acc.z * inv; o.w = acc.w * inv;
    o.x = o.x > 0.f ? o.x : __expf(o.x) - 1.f;
    o.y = o.y > 0.f ? o.y : __expf(o.y) - 1.f;
    o.z = o.z > 0.f ? o.z : __expf(o.z) - 1.f;
    o.w = o.w > 0.f ? o.w : __expf(o.w) - 1.f;
    ((float4*)Z)[(size_t)n * 64 + lane] = o;
}

__device__ __forceinline__ float fast_tanh(float x) {
    return 1.f - 2.f / (1.f + __expf(2.f * x));
}

// K5 v3: MFMA score with coalesced LDS staging.
// Block = 256 thr = 4 waves = 64 nodes. Stage Z (f32, contiguous 1KB/instr)
// -> bf16 LDS tile (row stride 264 shorts: ds_read_b128 bank-even).
// Wave w computes 16 nodes x 128 sems via 8 ks x 8 tt mfma_16x16x32_bf16.
// Reduction: wave shfl -> LDS -> 1 atomic per block into 16 bins.
__global__ void k_score(const float* __restrict__ Z,
                        const short* __restrict__ fcwb,
                        const float* __restrict__ fcb,
                        const float* __restrict__ q,
                        float* __restrict__ Sacc) {
    __shared__ short zs[64 * 264];     // 33792 B
    __shared__ float partial[4];
    int t = threadIdx.x;

    const float4* Zg4 = (const float4*)Z + (size_t)blockIdx.x * 4096;
    size_t gmax = (size_t)Nn * 64 - (size_t)blockIdx.x * 4096;
#pragma unroll
    for (int it = 0; it < 16; ++it) {
        int idx = it * 256 + t;
        if ((size_t)idx < gmax) {
            float4 v = Zg4[idx];
            int row = idx >> 6, c4 = idx & 63;
            s16x4 b;
            b[0] = f2bf(v.x); b[1] = f2bf(v.y); b[2] = f2bf(v.z); b[3] = f2bf(v.w);
            *(s16x4*)&zs[row * 264 + c4 * 4] = b;
        }
    }
    __syncthreads();

    int lane = t & 63;
    int wid = t >> 6;
    int nodebase = blockIdx.x * 64 + wid * 16;
    float local = 0.f;
    if (nodebase < Nn) {
        int col = lane & 15;
        int quad = lane >> 4;

        f32x4 acc[8];
#pragma unroll
        for (int tt = 0; tt < 8; ++tt) { acc[tt][0] = 0.f; acc[tt][1] = 0.f; acc[tt][2] = 0.f; acc[tt][3] = 0.f; }

        const short* zrow = &zs[(wid * 16 + col) * 264 + quad * 8];
        const short* brow = fcwb + (size_t)col * Cc + quad * 8;
#pragma unroll
        for (int ks = 0; ks < 8; ++ks) {
            bf16x8 a = *(const bf16x8*)(zrow + ks * 32);
            bf16x8 bf[8];
#pragma unroll
            for (int tt = 0; tt < 8; ++tt)
                bf[tt] = *(const bf16x8*)(brow + tt * 4096 + ks * 32);
#pragma unroll
            for (int tt = 0; tt < 8; ++tt)
                acc[tt] = __builtin_amdgcn_mfma_f32_16x16x32_bf16(a, bf[tt], acc[tt], 0, 0, 0);
        }

#pragma unroll
        for (int tt = 0; tt < 8; ++tt) {
            int n = tt * 16 + col;
            float b = fcb[n], qq = q[n];
#pragma unroll
            for (int r = 0; r < 4; ++r) local += fast_tanh(acc[tt][r] + b) * qq;
        }
    }
#pragma unroll
    for (int off = 32; off > 0; off >>= 1) local += __shfl_down(local, off);
    if (lane == 0) partial[wid] = local;
    __syncthreads();
    if (t == 0) {
        float s = partial[0] + partial[1] + partial[2] + partial[3];
        atomicAdd(&Sacc[blockIdx.x & 15], s);
    }
}

// K7: out = V0*out + V1*Z2; V from 16+16 score bins (uniform scalar loads).
__global__ __launch_bounds__(256) void k_combine(float* __restrict__ out,
                                                 const float* __restrict__ Z2,
                                                 const float* __restrict__ S) {
    float s1 = 0.f, s2 = 0.f;
#pragma unroll
    for (int i = 0; i < 16; ++i) { s1 += S[i]; s2 += S[16 + i]; }
    s1 *= (1.f / (float)Nn);
    s2 *= (1.f / (float)Nn);
    float mx = fmaxf(s1, s2);
    float e1 = __expf(s1 - mx), e2 = __expf(s2 - mx);
    float inv = 1.f / (e1 + e2);
    float V0 = e1 * inv, V1 = e2 * inv;
    size_t i = (size_t)blockIdx.x * 256 + threadIdx.x;
    if (i < (size_t)Nn * 64) {
        float4 a = ((float4*)out)[i];
        float4 b = ((const float4*)Z2)[i];
        a.x = V0 * a.x + V1 * b.x;
        a.y = V0 * a.y + V1 * b.y;
        a.z = V0 * a.z + V1 * b.z;
        a.w = V0 * a.w + V1 * b.w;
        ((float4*)out)[i] = a;
    }
}

extern "C" void kernel_launch(void* const* d_in, const int* in_sizes, int n_in,
                              void* d_out, int out_size, void* d_ws, size_t ws_size,
                              hipStream_t stream) {
    const float* x    = (const float*)d_in[0];
    const float* W    = (const float*)d_in[1];
    const float* att1 = (const float*)d_in[2];
    const float* att2 = (const float*)d_in[3];
    const float* fcw  = (const float*)d_in[4];
    const float* fcb  = (const float*)d_in[5];
    const float* q    = (const float*)d_in[6];
    const int*   ei1  = (const int*)d_in[7];
    const int*   ei2  = (const int*)d_in[8];
    int E1 = in_sizes[7] / 2;
    int E2 = in_sizes[8] / 2;
    float* out = (float*)d_out;

    char* ws = (char*)d_ws;
    size_t off = 0;
    auto alloc = [&](size_t bytes) -> char* {
        char* p = ws + off;
        off = (off + bytes + 255) & ~(size_t)255;
        return p;
    };
    float* Z2   = (float*)alloc((size_t)Nn * Cc * 4);
    float* h    = (float*)alloc((size_t)Nn * Dd * 4);
    float* sd1  = (float*)alloc((size_t)Nn * Hh * 4);
    float* ss1  = (float*)alloc((size_t)Nn * Hh * 4);
    float* sd2  = (float*)alloc((size_t)Nn * Hh * 4);
    float* ss2  = (float*)alloc((size_t)Nn * Hh * 4);
    int*   cnt  = (int*)alloc((size_t)2 * Nn * 4);
    float* red  = (float*)alloc(256);          // 16 bins S1, 16 bins S2
    float* Wt   = (float*)alloc((size_t)Dd * Cc * 4);
    short* fcwb = (short*)alloc((size_t)SEMk * Cc * 2);
    int*   slt1 = (int*)alloc((size_t)Nn * PAD * 4);
    int*   slt2 = (int*)alloc((size_t)Nn * PAD * 4);
    (void)ws_size; (void)n_in; (void)out_size;

    hipMemsetAsync(cnt, 0, (size_t)2 * Nn * 4, stream);
    hipMemsetAsync(red, 0, 256, stream);

    k_wtrans<<<(Dd * Cc + 255) / 256, 256, 0, stream>>>(W, Wt);
    k_fcwb<<<(SEMk * Cc + 255) / 256, 256, 0, stream>>>(fcw, fcwb);
    k_hproj<<<Nn / 32, 256, 0, stream>>>(x, Wt, att1, att2, h, sd1, ss1, sd2, ss2);
    k_scatter<<<(E1 + 255) / 256, 256, 0, stream>>>(ei1, E1, cnt, slt1);
    k_scatter<<<(E2 + 255) / 256, 256, 0, stream>>>(ei2, E2, cnt + Nn, slt2);
    k_gat<<<(Nn * 64) / 256, 256, 0, stream>>>(h, sd1, ss1, cnt, slt1, out);
    k_gat<<<(Nn * 64) / 256, 256, 0, stream>>>(h, sd2, ss2, cnt + Nn, slt2, Z2);
    int nblk = (Nn + 63) / 64;                 // 1563
    k_score<<<nblk, 256, 0, stream>>>(out, fcwb, fcb, q, red);
    k_score<<<nblk, 256, 0, stream>>>(Z2, fcwb, fcb, q, red + 16);
    k_combine<<<(Nn * 64) / 256, 256, 0, stream>>>(out, Z2, red);
}